// Round 6
// baseline (275.750 us; speedup 1.0000x reference)
//
#include <hip/hip_runtime.h>
#include <stdint.h>

// SGRSelector: per-row exact top-K indices, sorted (value desc, idx asc).
// B=256, S=131072, K=16384. Output int32 [B,K] ++ scalar K.
//
// R12: occupancy-first split (R11 post-mortem: select was latency-bound at
// 1 block/CU; fill kernel proves TLP saturates HBM at 6.9 TB/s).
//  K1 capture : 8 blocks/row x 256 thr (8 blocks/CU, 32 waves/CU). Stream
//               chunk, ballot-compact captured (u >= ordered(1.0625)) into
//               per-(chunk,wave) segments; 2064-bin LDS hist of high bins
//               (captured only) -> global per-row hist (~40 atomics/block).
//  K2 scangth : 1 block/row x 1024 thr. Load row hist (8 KB), suffix scan,
//               b1, cursors, worklists; gather the ~19K captured keys
//               (L2/L3-hot) into cand buckets. Fallbacks (segment overflow /
//               captured < K) re-read the row: exact for any input.
//  K3 sort    : unchanged proven ranking kernel.

#define S_LEN   131072
#define K_SEL   16384
#define NBINS   8192          // 2^13 buckets on top-13 bits
#define LOWBITS 19
#define IDXMASK 0x1FFFFu      // 17 bits of index
#define CAND_CAP 20480        // >= suffix[b1] ~ 18100 (max bucket <= 4096, R3)
#define SORT_CAP 4096
#define DIRECT_MAX 256
#define WL_PER_ROW 2048
#define D_GRID  2048
#define HCAP 256
#define LCAP 512
// capture threshold ordered(1.0625f); bucket(1.0625) = 6129.
#define U0_THRESH 0xBF880000u
#define HI0  6128             // first tracked bin (<= 6129)
#define NHI  (NBINS - HI0)    // 2064 tracked bins
// K1 geometry: 8 chunks/row, 256 thr (4 waves), 16 float4-iters/thread.
#define NCH     8
#define CH_LEN  (S_LEN / NCH)          // 16384 elems
#define K1ITER  (CH_LEN / 4 / 256)     // 16
#define NSEG    (NCH * 4)              // 32 segments/row
#define PC_SEG  832                    // per-segment cap (mean 591, sigma 22.5)

__device__ __forceinline__ unsigned int ordered_u32(float f) {
  // Monotonic float->uint: larger float => larger uint.
  unsigned int x = __float_as_uint(f);
  unsigned int mask = (unsigned int)((int)x >> 31) | 0x80000000u;
  return x ^ mask;
}

// ---------- K1: high-occupancy capture + small histogram ----------
__global__ __launch_bounds__(256)
void capture_kernel(const float* __restrict__ in,
                    unsigned long long* __restrict__ pairs,
                    unsigned int* __restrict__ segcnt,
                    unsigned int* __restrict__ rowhist,
                    unsigned int* __restrict__ rowflag) {
  const int row   = blockIdx.x >> 3;
  const int chunk = blockIdx.x & 7;
  const int tid   = threadIdx.x;
  const int lane  = tid & 63, wave = tid >> 6;          // 4 waves
  __shared__ unsigned int hh[NHI];                      // 8.25 KB
  for (int i = tid; i < NHI; i += 256) hh[i] = 0;
  __syncthreads();

  const float4* p = (const float4*)(in + (size_t)row * S_LEN + (size_t)chunk * CH_LEN);
  unsigned long long* seg =
      pairs + ((size_t)row * NSEG + (size_t)(chunk * 4 + wave)) * PC_SEG;
  unsigned int base = 0;                                // wave-uniform cursor
  const unsigned long long lmask = (1ull << lane) - 1ull;

#define CAP1(U, IDX) do {                                                    \
    unsigned int u_ = (U);                                                   \
    bool pred_ = (u_ >= U0_THRESH);                                          \
    unsigned long long m_ = __ballot(pred_);                                 \
    if (pred_) {                                                             \
      atomicAdd(&hh[(u_ >> LOWBITS) - HI0], 1u);                             \
      unsigned int pos_ = base + (unsigned int)__popcll(m_ & lmask);         \
      if (pos_ < PC_SEG)                                                     \
        seg[pos_] = ((unsigned long long)u_ << 17) |                         \
                    (unsigned long long)(IDXMASK - (unsigned int)(IDX));     \
    }                                                                        \
    base += (unsigned int)__popcll(m_); } while (0)

#pragma unroll 2
  for (int it = 0; it < K1ITER; ++it) {
    int i4 = it * 256 + tid;
    float4 v = p[i4];
    int idx0 = chunk * CH_LEN + i4 * 4;                 // index within row
    CAP1(ordered_u32(v.x), idx0 + 0);
    CAP1(ordered_u32(v.y), idx0 + 1);
    CAP1(ordered_u32(v.z), idx0 + 2);
    CAP1(ordered_u32(v.w), idx0 + 3);
  }
#undef CAP1
  if (lane == 0) {
    segcnt[row * NSEG + chunk * 4 + wave] = base;
    if (base > PC_SEG) rowflag[row] = 1u;               // race-ok
  }
  __syncthreads();
  // merge nonzero bins into per-row global hist (~40 nonzero bins)
  unsigned int* rh = rowhist + (size_t)row * NHI;
  for (int i = tid; i < NHI; i += 256) {
    unsigned int c = hh[i];
    if (c) atomicAdd(&rh[i], c);
  }
}

// Suffix scan over h[NBINS] -> sfx[NBINS]; threshold bucket -> *sb1p
// (sentinel 0xFFFFFFFF if total < K). Uniform control flow; has barriers.
__device__ __forceinline__ void suffix_scan_8k(const unsigned int* h,
                                               unsigned int* sfx,
                                               unsigned int* waveTot,
                                               unsigned int* sb1p,
                                               int tid, int lane, int wave) {
  if (tid == 0) *sb1p = 0xFFFFFFFFu;
  uint4 c0 = *(const uint4*)&h[tid * 8];
  uint4 c1 = *(const uint4*)&h[tid * 8 + 4];
  unsigned int v[8] = {c0.x, c0.y, c0.z, c0.w, c1.x, c1.y, c1.z, c1.w};
#pragma unroll
  for (int s = 6; s >= 0; --s) v[s] += v[s + 1];        // local suffix
  unsigned int tot = v[0];
  unsigned int suf = tot;
#pragma unroll
  for (int d = 1; d < 64; d <<= 1) {
    unsigned int o = __shfl_down(suf, d, 64);
    if (lane + d < 64) suf += o;
  }
  if (lane == 0) waveTot[wave] = suf;
  __syncthreads();
  unsigned int carry = 0;
  for (int w2 = wave + 1; w2 < 16; ++w2) carry += waveTot[w2];
  unsigned int addv = (suf - tot) + carry;              // from all higher threads
  {
    uint4 o0 = make_uint4(v[0] + addv, v[1] + addv, v[2] + addv, v[3] + addv);
    uint4 o1 = make_uint4(v[4] + addv, v[5] + addv, v[6] + addv, v[7] + addv);
    *(uint4*)&sfx[tid * 8]     = o0;
    *(uint4*)&sfx[tid * 8 + 4] = o1;
  }
  __syncthreads();
#pragma unroll
  for (int s = 0; s < 8; ++s) {
    int b = tid * 8 + s;
    unsigned int cur = sfx[b];
    unsigned int nxt = (b + 1 < NBINS) ? sfx[b + 1] : 0u;
    if (cur >= K_SEL && nxt < K_SEL) *sb1p = (unsigned int)b;   // unique b
  }
  __syncthreads();
}

// ---------- K2: scan + worklists + gather (1 block/row) ----------
__global__ __launch_bounds__(1024)
void scan_gather_kernel(const float* __restrict__ in,
                        const unsigned long long* __restrict__ pairs,
                        const unsigned int* __restrict__ segcnt,
                        const unsigned int* __restrict__ rowhist,
                        const unsigned int* __restrict__ rowflag,
                        unsigned long long* __restrict__ cand,
                        uint4* __restrict__ wl, unsigned int* __restrict__ ctrs,
                        unsigned int wlHalf, int* __restrict__ out,
                        int B, long long out_size) {
  const int row  = blockIdx.x;
  const int tid  = threadIdx.x;
  const int lane = tid & 63, wave = tid >> 6;           // 16 waves
  __shared__ unsigned int h[NBINS];
  __shared__ unsigned int sfx[NBINS];
  __shared__ unsigned int waveTot[16];
  __shared__ unsigned int sb1, nH, nL, gHs, gLs;
  __shared__ uint2 lheavy[HCAP];
  __shared__ uint2 llight[LCAP];

  // init h: zero low bins, copy exact high-bin counts from rowhist
  for (int i = tid; i < HI0; i += 1024) h[i] = 0;
  for (int i = tid; i < NHI; i += 1024) h[HI0 + i] = rowhist[(size_t)row * NHI + i];
  if (tid == 0) { nH = 0; nL = 0; }
  __syncthreads();

  const bool ovf = (rowflag[row] != 0u);
  const float4* p = (const float4*)(in + (size_t)row * S_LEN);
  if (ovf) {
    // segment overflow (pathological): rebuild FULL hist from the row.
    for (int i = tid; i < NBINS; i += 1024) h[i] = 0;
    __syncthreads();
    for (int it = 0; it < 32; ++it) {
      float4 v4 = p[it * 1024 + tid];
      float f[4] = {v4.x, v4.y, v4.z, v4.w};
#pragma unroll
      for (int e = 0; e < 4; ++e)
        atomicAdd(&h[ordered_u32(f[e]) >> LOWBITS], 1u);
    }
    __syncthreads();
  }

  suffix_scan_8k(h, sfx, waveTot, &sb1, tid, lane, wave);
  bool found1 = (sb1 != 0xFFFFFFFFu);
  if (!found1) {
    // captured < K (pathological): add the LOW bins (high bins exact), rescan.
    for (int it = 0; it < 32; ++it) {
      float4 v4 = p[it * 1024 + tid];
      float f[4] = {v4.x, v4.y, v4.z, v4.w};
#pragma unroll
      for (int e = 0; e < 4; ++e) {
        unsigned int u = ordered_u32(f[e]);
        if (u < U0_THRESH) atomicAdd(&h[u >> LOWBITS], 1u);
      }
    }
    __syncthreads();
    suffix_scan_8k(h, sfx, waveTot, &sb1, tid, lane, wave);
  }
  const unsigned int b1 = sb1;                          // always found now
  const bool fast = found1 && !ovf;

  // cursors (h[b] = bucket start) + local worklists
  for (int i = tid; i < NBINS; i += 1024) {
    unsigned int end   = sfx[i];
    unsigned int start = (i + 1 < NBINS) ? sfx[i + 1] : 0u;
    h[i] = start;                                       // gather cursor
    if ((unsigned int)i >= b1) {
      unsigned int cnt2 = end - start;
      if (cnt2) {
        if (cnt2 > DIRECT_MAX) {
          unsigned int p2 = atomicAdd(&nH, 1u);
          if (p2 < HCAP) lheavy[p2] = make_uint2(start, end);
          else {
            unsigned int g = atomicAdd(&ctrs[0], 1u);
            if (g < wlHalf) wl[2 * wlHalf - 1 - g] = make_uint4((unsigned int)row, start, end, 0u);
          }
        } else {
          unsigned int p2 = atomicAdd(&nL, 1u);
          if (p2 < LCAP) llight[p2] = make_uint2(start, end);
          else {
            unsigned int g = atomicAdd(&ctrs[1], 1u);
            if (g < wlHalf) wl[g] = make_uint4((unsigned int)row, start, end, 0u);
          }
        }
      }
    }
  }
  __syncthreads();
  if (tid == 0) {                                       // bulk reserve: 2 atomics/block
    gHs = atomicAdd(&ctrs[0], nH < HCAP ? nH : HCAP);
    gLs = atomicAdd(&ctrs[1], nL < LCAP ? nL : LCAP);
  }
  __syncthreads();
  {
    unsigned int hN = nH < HCAP ? nH : HCAP;
    unsigned int lN = nL < LCAP ? nL : LCAP;
    for (unsigned int i = tid; i < hN; i += 1024) {
      uint2 e = lheavy[i]; unsigned int pos = gHs + i;
      if (pos < wlHalf) wl[2 * wlHalf - 1 - pos] = make_uint4((unsigned int)row, e.x, e.y, 0u);
    }
    for (unsigned int i = tid; i < lN; i += 1024) {
      uint2 e = llight[i]; unsigned int pos = gLs + i;
      if (pos < wlHalf) wl[pos] = make_uint4((unsigned int)row, e.x, e.y, 0u);
    }
  }

  // gather: fast path scans the 32 captured segments (2 per wave, L2/L3-hot)
  unsigned long long* c = cand + (size_t)row * CAND_CAP;
  if (fast) {
#pragma unroll
    for (int sI = 0; sI < 2; ++sI) {
      const int s = wave * 2 + sI;
      const unsigned int cntS = segcnt[row * NSEG + s]; // <= PC_SEG (fast)
      const unsigned long long* sg = pairs + ((size_t)row * NSEG + s) * PC_SEG;
      for (unsigned int i = (unsigned int)lane; i < cntS; i += 64u) {
        unsigned long long k = sg[i];
        unsigned int b = (unsigned int)(k >> 36);
        if (b >= b1) {
          unsigned int pos = atomicAdd(&h[b], 1u);
          if (pos < CAND_CAP) c[pos] = k;
        }
      }
    }
  } else {
    for (int it = 0; it < 32; ++it) {
      int i4 = it * 1024 + tid;
      float4 v4 = p[i4];
      int idx0 = i4 * 4;
      float f[4] = {v4.x, v4.y, v4.z, v4.w};
#pragma unroll
      for (int e = 0; e < 4; ++e) {
        unsigned int u = ordered_u32(f[e]);
        unsigned int b = u >> LOWBITS;
        if (b >= b1) {
          unsigned int pos = atomicAdd(&h[b], 1u);
          unsigned long long key =
              ((unsigned long long)u << 17) |
              (unsigned long long)(IDXMASK - (unsigned int)(idx0 + e));
          if (pos < CAND_CAP) c[pos] = key;
        }
      }
    }
  }
  if (row == 0 && tid == 0) {
    long long pos = (long long)B * K_SEL;
    if (pos < out_size) out[pos] = K_SEL;
  }
}

// ---------- K3: static-stride per-bucket exact ranking (unchanged) ----------
__global__ __launch_bounds__(256)
void sort_kernel(const uint4* __restrict__ wl, const unsigned int* __restrict__ ctrs,
                 unsigned int wlHalf, const unsigned long long* __restrict__ cand,
                 int* __restrict__ out) {
  const int tid  = threadIdx.x;            // 256 threads, 4 waves
  const int lane = tid & 63, wave = tid >> 6;
  __shared__ unsigned int   skey2[SORT_CAP];   // 16 KiB: low-28 key bits
  __shared__ unsigned char  sdig2[SORT_CAP];   //  4 KiB: 8-bit digit
  __shared__ unsigned int   ssfx[257];
  __shared__ unsigned int   scur[256];
  __shared__ unsigned int   segTot[4];
  unsigned int nHeavy = ctrs[0]; if (nHeavy > wlHalf) nHeavy = wlHalf;
  unsigned int nLight = ctrs[1]; if (nLight > wlHalf) nLight = wlHalf;

  // ---- heavy phase (count > 256): register-staged keys, ONE global read ----
  for (unsigned int w = blockIdx.x; w < nHeavy; w += gridDim.x) {
    const uint4 it = wl[2 * wlHalf - 1 - w];
    const unsigned int row = it.x, start = it.y;
    unsigned int count = it.z - start;
    if (count > SORT_CAP) count = SORT_CAP;      // proven never hit (R3)
    const unsigned long long* c = cand + (size_t)row * CAND_CAP + start;
    int* orow = out + (size_t)row * K_SEL;

    unsigned long long me[16];
#pragma unroll
    for (int j = 0; j < 16; ++j) {
      unsigned int i = (unsigned int)tid + 256u * j;
      me[j] = (i < count) ? c[i] : 0ull;
    }
    scur[tid] = 0;
    __syncthreads();
#pragma unroll
    for (int j = 0; j < 16; ++j) {
      unsigned int i = (unsigned int)tid + 256u * j;
      if (i < count) atomicAdd(&scur[(unsigned int)(me[j] >> 28) & 255u], 1u);
    }
    __syncthreads();
    unsigned int cnt = scur[tid];
    unsigned int suf = cnt;
#pragma unroll
    for (int d = 1; d < 64; d <<= 1) {
      unsigned int o = __shfl_down(suf, d, 64);
      if (lane + d < 64) suf += o;
    }
    if (lane == 0) segTot[wave] = suf;
    __syncthreads();
    unsigned int carry = 0;
    for (int w2 = wave + 1; w2 < 4; ++w2) carry += segTot[w2];
    ssfx[tid] = suf + carry;                     // # elements with digit >= tid
    if (tid == 0) ssfx[256] = 0;
    __syncthreads();
    scur[tid] = ssfx[tid + 1];                   // digit range start cursor
    __syncthreads();
#pragma unroll
    for (int j = 0; j < 16; ++j) {
      unsigned int i = (unsigned int)tid + 256u * j;
      if (i < count) {
        unsigned long long k = me[j];
        unsigned int d = (unsigned int)(k >> 28) & 255u;
        unsigned int p = atomicAdd(&scur[d], 1u);
        skey2[p] = (unsigned int)k & 0x0FFFFFFFu;
        sdig2[p] = (unsigned char)d;
      }
    }
    __syncthreads();
    for (unsigned int p = tid; p < count; p += 256) {
      unsigned int k = skey2[p];
      unsigned int d = sdig2[p];
      unsigned int lo = ssfx[d + 1], hi = ssfx[d];
      unsigned int r = 0;
      for (unsigned int q = lo; q < hi; ++q) r += (skey2[q] > k) ? 1u : 0u;
      unsigned int pos = start + lo + r;
      if (pos < K_SEL)
        orow[pos] = (int)(IDXMASK - (k & IDXMASK));
    }
    __syncthreads();
  }

  // ---- light phase (count <= 256): one item per WAVE, register-only rank ----
  for (unsigned int w = blockIdx.x * 4u + (unsigned int)wave; w < nLight;
       w += gridDim.x * 4u) {
    const uint4 it = wl[w];
    const unsigned int row = it.x, start = it.y;
    const unsigned int count = it.z - start;
    const unsigned long long* c = cand + (size_t)row * CAND_CAP + start;
    int* orow = out + (size_t)row * K_SEL;
    if (count <= 64) {                           // 1 key/lane
      unsigned long long me = ((unsigned int)lane < count) ? c[lane] : 0ull;
      unsigned int r = 0;
      for (int l = 0; l < 64; ++l)
        r += (__shfl(me, l, 64) > me) ? 1u : 0u;
      if ((unsigned int)lane < count) {
        unsigned int pos = start + r;
        if (pos < K_SEL)
          orow[pos] = (int)(IDXMASK - ((unsigned int)me & IDXMASK));
      }
    } else if (count <= 128) {                   // 2 keys/lane
      unsigned long long me[2];
#pragma unroll
      for (int e = 0; e < 2; ++e) {
        unsigned int i = (unsigned int)lane + 64u * e;
        me[e] = (i < count) ? c[i] : 0ull;
      }
      unsigned int r[2] = {0u, 0u};
#pragma unroll
      for (int e = 0; e < 2; ++e) {
        for (int l = 0; l < 64; ++l) {
          unsigned long long kj = __shfl(me[e], l, 64);
#pragma unroll
          for (int e2 = 0; e2 < 2; ++e2) r[e2] += (kj > me[e2]) ? 1u : 0u;
        }
      }
#pragma unroll
      for (int e = 0; e < 2; ++e) {
        unsigned int i = (unsigned int)lane + 64u * e;
        if (i < count) {
          unsigned int pos = start + r[e];
          if (pos < K_SEL)
            orow[pos] = (int)(IDXMASK - ((unsigned int)me[e] & IDXMASK));
        }
      }
    } else {                                     // 4 keys/lane
      unsigned long long me[4];
#pragma unroll
      for (int e = 0; e < 4; ++e) {
        unsigned int i = (unsigned int)lane + 64u * e;
        me[e] = (i < count) ? c[i] : 0ull;
      }
      unsigned int r[4] = {0u, 0u, 0u, 0u};
#pragma unroll
      for (int e = 0; e < 4; ++e) {
        for (int l = 0; l < 64; ++l) {
          unsigned long long kj = __shfl(me[e], l, 64);
#pragma unroll
          for (int e2 = 0; e2 < 4; ++e2) r[e2] += (kj > me[e2]) ? 1u : 0u;
        }
      }
#pragma unroll
      for (int e = 0; e < 4; ++e) {
        unsigned int i = (unsigned int)lane + 64u * e;
        if (i < count) {
          unsigned int pos = start + r[e];
          if (pos < K_SEL)
            orow[pos] = (int)(IDXMASK - ((unsigned int)me[e] & IDXMASK));
        }
      }
    }
  }
}

extern "C" void kernel_launch(void* const* d_in, const int* in_sizes, int n_in,
                              void* d_out, int out_size, void* d_ws, size_t ws_size,
                              hipStream_t stream) {
  const float* importance = (const float*)d_in[0];
  int B = in_sizes[0] / S_LEN;
  if (B < 1) B = 1;
  (void)n_in; (void)ws_size;

  const unsigned int wlCap  = (unsigned int)B * WL_PER_ROW;
  const unsigned int wlHalf = wlCap / 2;
  size_t pairBytes = (size_t)B * NSEG * PC_SEG * sizeof(unsigned long long); // 54.5 MB
  size_t candBytes = (size_t)B * CAND_CAP * sizeof(unsigned long long);      // 41.9 MB
  size_t wlBytes   = (size_t)wlCap * sizeof(uint4);                          //  8 MB
  size_t segcBytes = (size_t)B * NSEG * sizeof(unsigned int);                // 32 KB
  char* base = (char*)d_ws;
  unsigned long long* pairs = (unsigned long long*)base;
  unsigned long long* cand  = (unsigned long long*)(base + pairBytes);
  uint4* wl                 = (uint4*)(base + pairBytes + candBytes);
  unsigned int* segcnt      = (unsigned int*)(base + pairBytes + candBytes + wlBytes);
  // zeroed region: ctrs(4) ++ rowflag(B) ++ rowhist(B*NHI), contiguous
  unsigned int* ctrs        = segcnt + (size_t)B * NSEG;
  unsigned int* rowflag     = ctrs + 4;
  unsigned int* rowhist     = rowflag + B;
  size_t zeroBytes = (4 + (size_t)B + (size_t)B * NHI) * sizeof(unsigned int); // ~2.1 MB
  int* out = (int*)d_out;
  (void)segcBytes;

  hipMemsetAsync(ctrs, 0, zeroBytes, stream);
  capture_kernel<<<dim3(B * NCH), dim3(256), 0, stream>>>(
      importance, pairs, segcnt, rowhist, rowflag);
  scan_gather_kernel<<<dim3(B), dim3(1024), 0, stream>>>(
      importance, pairs, segcnt, rowhist, rowflag, cand, wl, ctrs, wlHalf,
      out, B, (long long)out_size);
  sort_kernel<<<dim3(D_GRID), dim3(256), 0, stream>>>(wl, ctrs, wlHalf, cand, out);
}